// Round 4
// baseline (18857.475 us; speedup 1.0000x reference)
//
#include <hip/hip_runtime.h>

typedef unsigned short u16;
typedef __attribute__((ext_vector_type(4))) float f32x4;
typedef __attribute__((ext_vector_type(8))) short short8;

#define B_ 64
#define L_ 196
#define D_ 512
#define T_ 31
#define V_ 32000

__device__ __forceinline__ float b2f(unsigned int u) {
    union { float f; unsigned int u; } x; x.u = u << 16; return x.f;
}
__device__ __forceinline__ u16 f2b(float f) {
    union { float f; unsigned int u; } x; x.f = f;
    unsigned int r = x.u + 0x7fffu + ((x.u >> 16) & 1u);
    return (u16)(r >> 16);
}
// 8 bf16 (uint4) * 8 f32 -> acc
__device__ __forceinline__ void fma8(uint4 q, const float* x, float& acc) {
    acc += b2f(q.x & 0xffffu) * x[0]; acc += b2f(q.x >> 16) * x[1];
    acc += b2f(q.y & 0xffffu) * x[2]; acc += b2f(q.y >> 16) * x[3];
    acc += b2f(q.z & 0xffffu) * x[4]; acc += b2f(q.z >> 16) * x[5];
    acc += b2f(q.w & 0xffffu) * x[6]; acc += b2f(q.w >> 16) * x[7];
}

// ------------- bulk f32 -> bf16 convert, 4 elems/thread ----------------------
__global__ __launch_bounds__(256) void convert_kernel(
        const float* __restrict__ src, u16* __restrict__ dst, int n4) {
    int i = blockIdx.x * 256 + threadIdx.x;
    if (i >= n4) return;
    float4 v = *(const float4*)(src + (size_t)i * 4);
    u16* d = dst + (size_t)i * 4;
    d[0] = f2b(v.x); d[1] = f2b(v.y); d[2] = f2b(v.z); d[3] = f2b(v.w);
}

// ------------- prep: WfT, Wcat, Wemb, emb gather, bsum, zero flags -----------
__global__ __launch_bounds__(256) void prep_kernel(
        const float* __restrict__ Wfeat, const float* __restrict__ Wih,
        const float* __restrict__ Whh, const float* __restrict__ table,
        const int* __restrict__ cap, const float* __restrict__ bih,
        const float* __restrict__ bhh,
        u16* __restrict__ WfT, u16* __restrict__ Wcat,
        u16* __restrict__ Wemb, u16* __restrict__ Aemb,
        float* __restrict__ bsum, int* __restrict__ flags) {
    int idx = blockIdx.x * 256 + threadIdx.x;
    if (idx < 2048) { bsum[idx] = bih[idx] + bhh[idx]; flags[idx] = 0; }
    if (idx < 512 * 512) {
        WfT[idx] = f2b(Wfeat[(idx & 511) * 512 + (idx >> 9)]);
    }
    if (idx < 2048 * 1024) {
        int j = idx >> 10, k = idx & 1023;
        Wcat[idx] = f2b((k < 512) ? Wih[j * 1024 + 512 + k] : Whh[j * 512 + (k - 512)]);
    }
    if (idx < 2048 * 512) {
        int j = idx >> 9, k = idx & 511;
        Wemb[idx] = f2b(Wih[j * 1024 + k]);
    }
    if (idx < 1984 * 512) {
        int m = idx >> 9, k = idx & 511;       // m = t*64 + b
        int t = m >> 6, b = m & 63;
        Aemb[idx] = f2b(table[(size_t)cap[b * 32 + t] * 512 + k]);
    }
}

// ------------- persistent recurrence: 4 blocks per batch, flag-synced --------
// 256 blocks x 512 threads (1/CU, full machine). Block g -> (batch b, quarter
// q): b = (g&7)*8 + ((g>>3)&7), q = g>>6, so the 4 blocks of a group share an
// XCD under round-robin dispatch (perf-only assumption). Per step, 3 agent-
// scope group barriers:
//   A: hWh slice (128 d) + PARTIAL scores over the d-slice (relu elemwise in d)
//   B: redundant softmax over summed partials + context slice -> ctxf (f32)
//   C: gates GEMV for 128 h-dims (coalesced wave layout) + LSTM pointwise
// Cross-block state: ctxf/hf/spart f32 in global; c lives in block-local LDS.
__global__ __launch_bounds__(512, 2) void loop_kernel(
        const float* __restrict__ img,   // [64,196,512] f32
        const u16*   __restrict__ fpb,   // [12544,512] bf16 feat_proj
        const float* __restrict__ Wh,    // [512,512] f32
        const float* __restrict__ ab,    // [196]
        const float* __restrict__ va,    // [512]
        const u16*   __restrict__ Wcat,  // [2048,1024] bf16 rows: i,f,g,o
        const float* __restrict__ gemb,  // [1984,2048] f32 (biases folded in)
        float* __restrict__ ctxf,        // [64,512]  f32 context
        float* __restrict__ hf,          // [64,512]  f32 h
        float* __restrict__ spart,       // [64,4,256] f32 score partials
        int*   __restrict__ flags,       // [64,32] group counters (zeroed)
        u16*   __restrict__ hseq,        // [1984,512] bf16, row m = b*31+t
        float* __restrict__ alph) {      // [64,31,196]
    __shared__ __align__(16) float xf[1024];     // [context | h] f32 (local)
    __shared__ __align__(16) float hl[512];      // h(t-1) f32
    __shared__ float hw[128];                    // hWh slice
    __shared__ float red[512];
    __shared__ float gl[512];                    // gate pre-activations (slice)
    __shared__ float al[196];
    __shared__ float abl[196];
    __shared__ float sl[256];
    __shared__ float c_sl[128];                  // cell state slice (persists)

    int g = blockIdx.x;
    int b = (g & 7) * 8 + ((g >> 3) & 7);
    int q = g >> 6;
    int tid = threadIdx.x, lane = tid & 63, wv = tid >> 6;
    int* ctr = flags + b * 32;
    int nb = 0;

#define GSYNC() do {                                                          \
        nb++;                                                                 \
        __threadfence();                                                      \
        __syncthreads();                                                      \
        if (tid == 0) {                                                       \
            __hip_atomic_fetch_add(ctr, 1, __ATOMIC_RELEASE,                  \
                                   __HIP_MEMORY_SCOPE_AGENT);                 \
            while (__hip_atomic_load(ctr, __ATOMIC_ACQUIRE,                   \
                                     __HIP_MEMORY_SCOPE_AGENT) < nb * 4)      \
                __builtin_amdgcn_s_sleep(2);                                  \
            __threadfence();                                                  \
        }                                                                     \
        __syncthreads();                                                      \
    } while (0)

    if (tid < 196) abl[tid] = ab[tid];
    float va0 = va[q * 128 + lane * 2], va1 = va[q * 128 + lane * 2 + 1];
    int dq = tid & 127, ls = tid >> 7;           // d-slice lane / l-stride id

    // ---- prologue: h0 = c0 = mean_l(img[b,:,slice]) ------------------------
    {
        const float* ib = img + ((size_t)b * L_) * D_ + q * 128 + dq;
        float acc = 0.f;
        for (int l = ls; l < L_; l += 4) acc += ib[(size_t)l * D_];
        red[tid] = acc;
        __syncthreads();
        if (tid < 128) {
            float m = (red[tid] + red[tid + 128] + red[tid + 256] + red[tid + 384])
                      * (1.0f / 196.0f);
            c_sl[tid] = m;
            hf[b * 512 + q * 128 + tid] = m;
        }
    }
    GSYNC();

    for (int t = 0; t < T_; t++) {
        // ---------------- A: hWh slice + partial scores ---------------------
        hl[tid] = hf[b * 512 + tid];
        __syncthreads();
        {
            int dd = q * 128 + dq;
            int k0 = ls * 128;
            const float* wp = Wh + dd;
            float acc = 0.f;
#pragma unroll 4
            for (int k = k0; k < k0 + 128; k++) acc += hl[k] * wp[(size_t)k * 512];
            red[tid] = acc;
        }
        __syncthreads();
        if (tid < 128) hw[tid] = red[tid] + red[tid + 128] + red[tid + 256] + red[tid + 384];
        __syncthreads();
        {
            float h0 = hw[lane * 2], h1 = hw[lane * 2 + 1];
            for (int l = wv; l < L_; l += 8) {
                unsigned fp2 = *(const unsigned*)(fpb + ((size_t)(b * L_ + l)) * D_
                                                  + q * 128 + lane * 2);
                float abv = abl[l];
                float a0 = fmaxf(b2f(fp2 & 0xffffu) + h0 + abv, 0.f);
                float a1 = fmaxf(b2f(fp2 >> 16) + h1 + abv, 0.f);
                float acc = a0 * va0 + a1 * va1;
#pragma unroll
                for (int off = 32; off; off >>= 1) acc += __shfl_xor(acc, off, 64);
                if (lane == 0) spart[(b * 4 + q) * 256 + l] = acc;
            }
        }
        GSYNC();
        // ---------------- B: softmax (redundant) + context slice ------------
        {
            float s = -3.4e38f;
            if (tid < L_) {
                const float* sp = spart + b * 4 * 256 + tid;
                s = sp[0] + sp[256] + sp[512] + sp[768];
            }
            if (tid < 256) sl[tid] = s;
            __syncthreads();
            for (int off = 128; off; off >>= 1) {
                if (tid < off) sl[tid] = fmaxf(sl[tid], sl[tid + off]);
                __syncthreads();
            }
            float mx = sl[0];
            __syncthreads();
            float e = (tid < L_) ? expf(s - mx) : 0.f;
            if (tid < L_) al[tid] = e;
            if (tid < 256) sl[tid] = e;
            __syncthreads();
            for (int off = 128; off; off >>= 1) {
                if (tid < off) sl[tid] += sl[tid + off];
                __syncthreads();
            }
            float inv = 1.f / sl[0];
            if (tid < L_) {
                float a = al[tid] * inv;
                al[tid] = a;
                if (q == 0) alph[((size_t)(b * T_ + t)) * L_ + tid] = a;
            }
            __syncthreads();
            const float* ib = img + ((size_t)b * L_) * D_ + q * 128 + dq;
            float acc = 0.f;
            for (int l = ls; l < L_; l += 4) acc += al[l] * ib[(size_t)l * D_];
            red[tid] = acc;
            __syncthreads();
            if (tid < 128)
                ctxf[b * 512 + q * 128 + tid] =
                    red[tid] + red[tid + 128] + red[tid + 256] + red[tid + 384];
        }
        GSYNC();
        // ---------------- C: gates GEMV slice + LSTM pointwise --------------
        {
            xf[tid] = ctxf[b * 512 + tid];
            xf[512 + tid] = hl[tid];
            __syncthreads();
            int rsub = lane >> 3, ksub = lane & 7;
#pragma unroll
            for (int p = 0; p < 8; p++) {
                int rl = p * 64 + wv * 8 + rsub;          // 0..511 unique
                int row = (rl >> 7) * 512 + q * 128 + (rl & 127);
                const u16* wr = Wcat + (size_t)row * 1024 + ksub * 8;
                float acc = 0.f;
#pragma unroll
                for (int kk = 0; kk < 16; kk++) {
                    uint4 qv = *(const uint4*)(wr + kk * 64);
                    fma8(qv, &xf[ksub * 8 + kk * 64], acc);
                }
                acc += __shfl_xor(acc, 1, 64);
                acc += __shfl_xor(acc, 2, 64);
                acc += __shfl_xor(acc, 4, 64);
                if (ksub == 0) gl[rl] = acc;
            }
            __syncthreads();
            if (tid < 128) {
                int j = tid;
                const float* ge = gemb + ((size_t)(t * 64 + b)) * 2048 + q * 128 + j;
                float gi = gl[j] + ge[0];
                float gf = gl[128 + j] + ge[512];
                float gg = gl[256 + j] + ge[1024];
                float go = gl[384 + j] + ge[1536];
                float si = 1.f / (1.f + expf(-gi));
                float sf = 1.f / (1.f + expf(-gf));
                float so = 1.f / (1.f + expf(-go));
                float cn = sf * c_sl[j] + si * tanhf(gg);
                c_sl[j] = cn;
                float hn = so * tanhf(cn);
                hf[b * 512 + q * 128 + j] = hn;
                hseq[((size_t)(b * T_ + t)) * 512 + q * 128 + j] = f2b(hn);
            }
        }
        GSYNC();
    }
#undef GSYNC
}

// ------------- generic MFMA GEMM: C[MxN] = A[MxK] @ B_T[NxK]^T ---------------
// 64x64 block tile, 4 waves 2x2, each wave 2x2 MFMA tiles of 16x16, BK=32
// MODE 0: C(bf16) = bf16(acc)       MODE 1: C(f32) = acc + bias[n] (NT store)
// MODE 2: C(f32) = acc              MODE 3: C(f32) = acc + bias[n]
// SWZ 1: XCD-bijective remap for the final 15500-block (500x31) GEMM.
template <int MODE, int SWZ>
__global__ __launch_bounds__(256) void gemm64_kernel(
        const u16* __restrict__ A, const u16* __restrict__ Bm,
        int lda, int ldb, int K, void* __restrict__ Cv, int ldc,
        const float* __restrict__ bias) {
    __shared__ __align__(16) u16 At[64 * 40];
    __shared__ __align__(16) u16 Bt[64 * 40];
    int tid = threadIdx.x, wave = tid >> 6, lane = tid & 63;
    int wm = (wave >> 1) * 32, wn = (wave & 1) * 32;
    size_t m0, n0;
    if (SWZ) {
        unsigned lin = blockIdx.y * gridDim.x + blockIdx.x;   // dispatch order
        const unsigned q = 15500u / 8u, r = 15500u % 8u;      // 1937, 4
        unsigned xcd = lin & 7u, pos = lin >> 3;
        unsigned wg = (xcd < r ? xcd * (q + 1u) : r * (q + 1u) + (xcd - r) * q) + pos;
        unsigned mt = wg % 31u, nt = wg / 31u;
        m0 = (size_t)mt * 64; n0 = (size_t)nt * 64;
    } else {
        m0 = (size_t)blockIdx.y * 64; n0 = (size_t)blockIdx.x * 64;
    }
    f32x4 acc[2][2];
#pragma unroll
    for (int i = 0; i < 2; i++)
#pragma unroll
        for (int j = 0; j < 2; j++) acc[i][j] = {0.f, 0.f, 0.f, 0.f};
    int sr = tid >> 2, sc = (tid & 3) * 8;
    const u16* Ap = A + (m0 + sr) * (size_t)lda + sc;
    const u16* Bp = Bm + (n0 + sr) * (size_t)ldb + sc;
    int fm = lane & 15, fk = (lane >> 4) * 8;
    for (int k0 = 0; k0 < K; k0 += 32) {
        uint4 av = *(const uint4*)(Ap + k0);
        uint4 bv = *(const uint4*)(Bp + k0);
        __syncthreads();
        *(uint4*)(&At[sr * 40 + sc]) = av;
        *(uint4*)(&Bt[sr * 40 + sc]) = bv;
        __syncthreads();
        short8 a0 = *(const short8*)(&At[(wm + fm) * 40 + fk]);
        short8 a1 = *(const short8*)(&At[(wm + 16 + fm) * 40 + fk]);
        short8 b0 = *(const short8*)(&Bt[(wn + fm) * 40 + fk]);
        short8 b1 = *(const short8*)(&Bt[(wn + 16 + fm) * 40 + fk]);
        acc[0][0] = __builtin_amdgcn_mfma_f32_16x16x32_bf16(a0, b0, acc[0][0], 0, 0, 0);
        acc[0][1] = __builtin_amdgcn_mfma_f32_16x16x32_bf16(a0, b1, acc[0][1], 0, 0, 0);
        acc[1][0] = __builtin_amdgcn_mfma_f32_16x16x32_bf16(a1, b0, acc[1][0], 0, 0, 0);
        acc[1][1] = __builtin_amdgcn_mfma_f32_16x16x32_bf16(a1, b1, acc[1][1], 0, 0, 0);
    }
    int crow = (lane >> 4) * 4, ccol = lane & 15;
#pragma unroll
    for (int mi = 0; mi < 2; mi++)
#pragma unroll
        for (int ni = 0; ni < 2; ni++)
#pragma unroll
            for (int r = 0; r < 4; r++) {
                size_t row = m0 + wm + mi * 16 + crow + r;
                size_t col = n0 + wn + ni * 16 + ccol;
                float v = acc[mi][ni][r];
                if (MODE == 0) {
                    ((u16*)Cv)[row * (size_t)ldc + col] = f2b(v);
                } else if (MODE == 1) {
                    v += bias[col];
                    __builtin_nontemporal_store(v, (float*)Cv + row * (size_t)ldc + col);
                } else {
                    if (MODE == 3) v += bias[col];
                    ((float*)Cv)[row * (size_t)ldc + col] = v;
                }
            }
}

extern "C" void kernel_launch(void* const* d_in, const int* in_sizes, int n_in,
                              void* d_out, int out_size, void* d_ws, size_t ws_size,
                              hipStream_t stream) {
    (void)in_sizes; (void)n_in; (void)out_size; (void)ws_size;
    const float* img   = (const float*)d_in[0];
    const int*   cap   = (const int*)d_in[1];
    const float* table = (const float*)d_in[2];
    const float* Wf    = (const float*)d_in[3];
    const float* Wh    = (const float*)d_in[4];
    const float* ab    = (const float*)d_in[5];
    const float* va    = (const float*)d_in[6];
    const float* Wih   = (const float*)d_in[7];
    const float* Whh   = (const float*)d_in[8];
    const float* bih   = (const float*)d_in[9];
    const float* bhh   = (const float*)d_in[10];
    const float* Wout  = (const float*)d_in[11];
    const float* bout  = (const float*)d_in[12];

    float* dout = (float*)d_out;                    // predictions [64,31,32000]
    float* alph = dout + (size_t)B_ * T_ * V_;      // alphas [64,31,196]

    char* w = (char*)d_ws;
    u16*   imgb  = (u16*)(w);                       // [12544,512] bf16
    u16*   fpb   = (u16*)(w + 12845056);            // [12544,512] bf16
    u16*   Woutb = (u16*)(w + 25690112);            // [32000,512] bf16
    u16*   Wcat  = (u16*)(w + 58458112);            // [2048,1024] bf16
    u16*   Wemb  = (u16*)(w + 62652416);            // [2048,512]  bf16
    u16*   WfT   = (u16*)(w + 64749568);            // [512,512]   bf16
    u16*   Aemb  = (u16*)(w + 65273856);            // [1984,512]  bf16
    u16*   hseq  = (u16*)(w + 67305472);            // [1984,512]  bf16
    float* gemb  = (float*)(w + 69337088);          // [1984,2048] f32
    float* bsum  = (float*)(w + 85590016);          // [2048]      f32
    float* ctxf  = (float*)(w + 85598208);          // [64,512]    f32
    float* hf    = (float*)(w + 85729280);          // [64,512]    f32
    float* spart = (float*)(w + 85860352);          // [64,4,256]  f32
    int*   flags = (int*)(w + 86122496);            // [64,32]     int

    // upfront conversions / packing
    convert_kernel<<<6272, 256, 0, stream>>>(img, imgb, 12544 * 512 / 4);
    convert_kernel<<<16000, 256, 0, stream>>>(Wout, Woutb, 32000 * 512 / 4);
    prep_kernel<<<8192, 256, 0, stream>>>(Wf, Wih, Whh, table, cap, bih, bhh,
                                          WfT, Wcat, Wemb, Aemb, bsum, flags);
    // feat_proj = img @ W_feat : [12544,512] -> bf16
    gemm64_kernel<0, 0><<<dim3(8, 196), 256, 0, stream>>>(imgb, WfT, 512, 512, 512, fpb, 512, nullptr);
    // gates_emb = emb @ W_ih[:, :512].T + (bih+bhh) : [1984,2048] -> f32
    gemm64_kernel<3, 0><<<dim3(32, 31), 256, 0, stream>>>(Aemb, Wemb, 512, 512, 512, gemb, 2048, bsum);

    // whole 31-step recurrence: 256 blocks, 4 per batch, flag-synced groups
    loop_kernel<<<256, 512, 0, stream>>>(img, fpb, Wh, ab, va, Wcat, gemb,
                                         ctxf, hf, spart, flags, hseq, alph);

    // predictions = hseq @ W_out.T + b_out : [1984,32000] -> f32 (XCD-swizzled)
    gemm64_kernel<1, 1><<<dim3(500, 31), 256, 0, stream>>>(hseq, Woutb, 512, 512, 512, dout, 32000, bout);
}